// Round 9
// baseline (528.818 us; speedup 1.0000x reference)
//
#include <hip/hip_runtime.h>
#include <float.h>

// Geometry
#define DI   64
#define DOUT 62
#define CI   3
#define CO   16
#define NB   16
constexpr int SP    = DOUT * DOUT * DOUT;   // 238328
constexpr int HBLK  = 16;                   // h tiles of 4
constexpr int DBLK  = 16;                   // d tiles of 4
constexpr int NPART = HBLK * DBLK;          // 256 partials per (n,c)

// Module BSS scratch (fully rewritten every call)
__device__ float g_psum[NB * CO * NPART];
__device__ float g_psq [NB * CO * NPART];
__device__ float g_stats[NB * CO * 2];

// ---------------------------------------------------------------------------
// Tiled conv: block (64,4) computes a [4d][4h][62w] x 16ch tile.
// LDS slab xs[i][p][hr][w]: 3*6*6*64 floats = 27.6 KB.
// Inner loop hoists 48 weights per (i,kh,kd) into registers (compile-time
// indexed -> VGPRs). Live set ~130 VGPR; NO __launch_bounds__ occupancy clamp
// (R8's ",4" capped VGPR at 64 and spilled acc[4][16] to scratch: +120 MB
// spill traffic, conv 317 us).
// ---------------------------------------------------------------------------
template <int MODE>  // 0 = stats only, 1 = stats + store y, 2 = recompute -> out
__global__ __launch_bounds__(256) void conv_kernel(
    const float* __restrict__ x, const float* __restrict__ wgt,
    const float* __restrict__ b, const float* __restrict__ m,
    float* __restrict__ yout)   // MODE1: y buffer; MODE2: final out
{
    const int tx = threadIdx.x;              // w lane 0..63
    const int ty = threadIdx.y;              // 0..3
    const int h0 = blockIdx.x * 4;
    const int d0 = blockIdx.y * 4;
    const int n  = blockIdx.z;
    const int h  = h0 + ty;

    __shared__ float xs[3 * 6 * 6 * 64];     // ((i*6+p)*6+hr)*64 + w

    const float* xn = x + (size_t)n * CI * DI * DI * DI;
    for (int rr = ty; rr < 108; rr += 4) {
        const int i  = rr / 36;
        const int rm = rr % 36;
        const int dg = min(d0 + rm / 6, DI - 1);
        const int hg = min(h0 + rm % 6, DI - 1);
        xs[rr * 64 + tx] = xn[((i * DI + dg) * DI + hg) * DI + tx];
    }
    __syncthreads();

    const bool active = (tx < DOUT) && (h < DOUT);

    float acc[4][CO];
#pragma unroll
    for (int dd = 0; dd < 4; ++dd)
#pragma unroll
        for (int o = 0; o < CO; ++o) acc[dd][o] = 0.f;

    if (active) {
#pragma unroll
        for (int i = 0; i < CI; ++i) {
#pragma unroll
            for (int kh = 0; kh < 3; ++kh) {
                const float* base = xs + (i * 36 + ty + kh) * 64 + tx;
#pragma unroll
                for (int kd = 0; kd < 3; ++kd) {
                    // 48 weights for this (i,kh,kd): wv[kr][o], uniform scalar loads
                    float wv[3][CO];
#pragma unroll
                    for (int o = 0; o < CO; ++o) {
                        const float* wp = wgt + o * 81 + i * 27 + kd * 9 + kh * 3;
                        wv[0][o] = wp[0]; wv[1][o] = wp[1]; wv[2][o] = wp[2];
                    }
#pragma unroll
                    for (int p = kd; p < kd + 4; ++p) {
                        const int dd = p - kd;
                        const float x0 = base[p * 384 + 0];
                        const float x1 = base[p * 384 + 1];
                        const float x2 = base[p * 384 + 2];
#pragma unroll
                        for (int o = 0; o < CO; ++o) {
                            acc[dd][o] = fmaf(x0, wv[0][o], acc[dd][o]);
                            acc[dd][o] = fmaf(x1, wv[1][o], acc[dd][o]);
                            acc[dd][o] = fmaf(x2, wv[2][o], acc[dd][o]);
                        }
                    }
                }
            }
        }
    }

    if (MODE == 2) {
        if (active) {
            float mx[4] = { -FLT_MAX, -FLT_MAX, -FLT_MAX, -FLT_MAX };
#pragma unroll
            for (int o = 0; o < CO; ++o) {
                const float mu = g_stats[(n * CO + o) * 2 + 0];
                const float is = g_stats[(n * CO + o) * 2 + 1];
                const float bo = b[o], mo = m[o];
#pragma unroll
                for (int dd = 0; dd < 4; ++dd) {
                    float v = (acc[dd][o] + bo) * mo;
                    v = (v - mu) * is;
                    v = fminf(fmaxf(v, -1.f), 1.f) * mo;
                    mx[dd] = fmaxf(mx[dd], v);
                }
            }
#pragma unroll
            for (int dd = 0; dd < 4; ++dd)
                if (d0 + dd < DOUT)
                    yout[(size_t)n * SP + ((d0 + dd) * DOUT + h) * DOUT + tx] = mx[dd];
        }
        return;
    }

    // MODE 0/1: bias+m, optional y store, block-level sum/sumsq partials
    __shared__ float redS[4][CO];
    __shared__ float redQ[4][CO];

#pragma unroll
    for (int o = 0; o < CO; ++o) {
        float s = 0.f, q = 0.f;
        if (active) {
            const float bo = b[o], mo = m[o];
#pragma unroll
            for (int dd = 0; dd < 4; ++dd) {
                if (d0 + dd < DOUT) {
                    const float v = (acc[dd][o] + bo) * mo;
                    s += v; q += v * v;
                    if (MODE == 1)
                        yout[(size_t)(n * CO + o) * SP + ((d0 + dd) * DOUT + h) * DOUT + tx] = v;
                }
            }
        }
#pragma unroll
        for (int off = 32; off > 0; off >>= 1) {
            s += __shfl_down(s, off);
            q += __shfl_down(q, off);
        }
        if (tx == 0) { redS[ty][o] = s; redQ[ty][o] = q; }
    }
    __syncthreads();

    if (ty == 0 && tx < CO) {
        const int o = tx;
        const float s = redS[0][o] + redS[1][o] + redS[2][o] + redS[3][o];
        const float q = redQ[0][o] + redQ[1][o] + redQ[2][o] + redQ[3][o];
        const int blk = blockIdx.x + HBLK * blockIdx.y;      // 0..255
        g_psum[(n * CO + o) * NPART + blk] = s;
        g_psq [(n * CO + o) * NPART + blk] = q;
    }
}

// Reduce 256 partials per (n,c) -> mean, invstd
__global__ __launch_bounds__(256) void finalize_stats_kernel()
{
    const int idx = blockIdx.x;              // n*16 + o
    const int tid = threadIdx.x;
    __shared__ float ls[256], lq[256];
    ls[tid] = g_psum[idx * NPART + tid];
    lq[tid] = g_psq [idx * NPART + tid];
    __syncthreads();
    for (int off = 128; off > 0; off >>= 1) {
        if (tid < off) { ls[tid] += ls[tid + off]; lq[tid] += lq[tid + off]; }
        __syncthreads();
    }
    if (tid == 0) {
        const float inv_n = 1.0f / (float)SP;
        const float mean = ls[0] * inv_n;
        const float var  = fmaxf(lq[0] * inv_n - mean * mean, 0.f);
        g_stats[idx * 2 + 0] = mean;
        g_stats[idx * 2 + 1] = rsqrtf(var + 1e-5f);
    }
}

// Memory-bound pass 2 when y was stored: read y, normalize, clamp, *m, max, store
__global__ __launch_bounds__(256) void pass2_ry_kernel(
    const float* __restrict__ y, const float* __restrict__ m,
    float* __restrict__ out)
{
    const int gid = blockIdx.x * 256 + threadIdx.x;
    if (gid >= NB * SP) return;
    const int n  = gid / SP;
    const int sp = gid % SP;

    float mx = -FLT_MAX;
#pragma unroll
    for (int o = 0; o < CO; ++o) {
        const float mu = g_stats[(n * CO + o) * 2 + 0];
        const float is = g_stats[(n * CO + o) * 2 + 1];
        float v = y[(size_t)(n * CO + o) * SP + sp];
        v = (v - mu) * is;
        v = fminf(fmaxf(v, -1.f), 1.f) * m[o];
        mx = fmaxf(mx, v);
    }
    out[gid] = mx;
}

extern "C" void kernel_launch(void* const* d_in, const int* in_sizes, int n_in,
                              void* d_out, int out_size, void* d_ws, size_t ws_size,
                              hipStream_t stream)
{
    const float* x = (const float*)d_in[0];
    const float* w = (const float*)d_in[1];
    const float* b = (const float*)d_in[2];
    const float* m = (const float*)d_in[3];
    float* out = (float*)d_out;

    const dim3 blk(64, 4);
    const dim3 grd(HBLK, DBLK, NB);
    const size_t yBytes = (size_t)NB * CO * SP * sizeof(float);   // ~244 MB

    if (ws_size >= yBytes) {
        float* y = (float*)d_ws;
        conv_kernel<1><<<grd, blk, 0, stream>>>(x, w, b, m, y);
        finalize_stats_kernel<<<dim3(NB * CO), dim3(256), 0, stream>>>();
        pass2_ry_kernel<<<dim3((NB * SP + 255) / 256), dim3(256), 0, stream>>>(y, m, out);
    } else {
        conv_kernel<0><<<grd, blk, 0, stream>>>(x, w, b, m, nullptr);
        finalize_stats_kernel<<<dim3(NB * CO), dim3(256), 0, stream>>>();
        conv_kernel<2><<<grd, blk, 0, stream>>>(x, w, b, m, out);
    }
}

// Round 10
// 193.734 us; speedup vs baseline: 2.7296x; 2.7296x over previous
//
#include <hip/hip_runtime.h>
#include <float.h>

// Geometry
#define DI   64
#define DOUT 62
#define CI   3
#define CO   16
#define NB   16
constexpr int SP    = DOUT * DOUT * DOUT;   // 238328
constexpr int HBLK  = 16;                   // h tiles of 4
constexpr int DBLK  = 16;                   // d tiles of 4
constexpr int NPART = HBLK * DBLK;          // 256 partials per (n,c)

// Module BSS scratch (fully rewritten every call)
__device__ float  g_psum[NB * CO * NPART];
__device__ float  g_psq [NB * CO * NPART];
__device__ float  g_stats[NB * CO * 2];
// Reorganized weights: [i][kh][kd][r] -> 16 channels contiguous, float4-aligned.
__device__ float4 g_wr4[CI * 3 * 3 * 3 * 4];   // 324 float4 = 5184 B

// Reorder w[o][i][kd][kh][r] -> g_wr[((i*3+kh)*3+kd)*3+r][o]
__global__ void reorg_w_kernel(const float* __restrict__ w)
{
    float* dst = (float*)g_wr4;
    for (int idx = threadIdx.x; idx < CO * CI * 27; idx += 256) {
        const int o  = idx / 81;
        const int t  = idx % 81;          // i*27 + kd*9 + kh*3 + r
        const int i  = t / 27;
        const int kd = (t % 27) / 9;
        const int kh = (t % 9) / 3;
        const int r  = t % 3;
        dst[((((i * 3 + kh) * 3 + kd) * 3) + r) * 16 + o] = w[idx];
    }
}

// ---------------------------------------------------------------------------
// Tiled conv: block (64,4) computes a [4d][4h][62w] x 16ch tile.
// LDS slab xs[i][p][hr][w]: 3*6*6*64 floats = 27.6 KB.
// Weights via per-lane-uniform float4 loads (vmcnt pipe) -> no lgkmcnt
// serialization with ds_reads (R9's s_load pathology). x cached across kd
// in xv[6][3]. ~115 live VGPRs; launch_bounds(256,3) caps at ~170.
// ---------------------------------------------------------------------------
template <int MODE>  // 0 = stats only, 1 = stats + store y, 2 = recompute -> out
__global__ __launch_bounds__(256, 3) void conv_kernel(
    const float* __restrict__ x,
    const float* __restrict__ b, const float* __restrict__ m,
    float* __restrict__ yout)   // MODE1: y buffer; MODE2: final out
{
    const int tx = threadIdx.x;              // w lane 0..63
    const int ty = threadIdx.y;              // 0..3
    const int h0 = blockIdx.x * 4;
    const int d0 = blockIdx.y * 4;
    const int n  = blockIdx.z;
    const int h  = h0 + ty;

    __shared__ float xs[3 * 6 * 6 * 64];     // ((i*6+p)*6+hr)*64 + w

    const float* xn = x + (size_t)n * CI * DI * DI * DI;
    for (int rr = ty; rr < 108; rr += 4) {
        const int i  = rr / 36;
        const int rm = rr % 36;
        const int dg = min(d0 + rm / 6, DI - 1);
        const int hg = min(h0 + rm % 6, DI - 1);
        xs[rr * 64 + tx] = xn[((i * DI + dg) * DI + hg) * DI + tx];
    }
    __syncthreads();

    const bool active = (tx < DOUT) && (h < DOUT);

    float acc[4][CO];
#pragma unroll
    for (int dd = 0; dd < 4; ++dd)
#pragma unroll
        for (int o = 0; o < CO; ++o) acc[dd][o] = 0.f;

    if (active) {
#pragma unroll
        for (int i = 0; i < CI; ++i) {
#pragma unroll
            for (int kh = 0; kh < 3; ++kh) {
                const float* base = xs + (i * 36 + ty + kh) * 64 + tx;
                // 18 x values, cached across kd
                float xv[6][3];
#pragma unroll
                for (int p = 0; p < 6; ++p) {
                    xv[p][0] = base[p * 384 + 0];
                    xv[p][1] = base[p * 384 + 1];
                    xv[p][2] = base[p * 384 + 2];
                }
#pragma unroll
                for (int kd = 0; kd < 3; ++kd) {
#pragma unroll
                    for (int r = 0; r < 3; ++r) {
                        const float4* wq = g_wr4 + ((((i * 3 + kh) * 3 + kd) * 3) + r) * 4;
                        const float4 w0 = wq[0], w1 = wq[1], w2 = wq[2], w3 = wq[3];
#pragma unroll
                        for (int dd = 0; dd < 4; ++dd) {
                            const float xx = xv[kd + dd][r];
                            acc[dd][ 0] = fmaf(xx, w0.x, acc[dd][ 0]);
                            acc[dd][ 1] = fmaf(xx, w0.y, acc[dd][ 1]);
                            acc[dd][ 2] = fmaf(xx, w0.z, acc[dd][ 2]);
                            acc[dd][ 3] = fmaf(xx, w0.w, acc[dd][ 3]);
                            acc[dd][ 4] = fmaf(xx, w1.x, acc[dd][ 4]);
                            acc[dd][ 5] = fmaf(xx, w1.y, acc[dd][ 5]);
                            acc[dd][ 6] = fmaf(xx, w1.z, acc[dd][ 6]);
                            acc[dd][ 7] = fmaf(xx, w1.w, acc[dd][ 7]);
                            acc[dd][ 8] = fmaf(xx, w2.x, acc[dd][ 8]);
                            acc[dd][ 9] = fmaf(xx, w2.y, acc[dd][ 9]);
                            acc[dd][10] = fmaf(xx, w2.z, acc[dd][10]);
                            acc[dd][11] = fmaf(xx, w2.w, acc[dd][11]);
                            acc[dd][12] = fmaf(xx, w3.x, acc[dd][12]);
                            acc[dd][13] = fmaf(xx, w3.y, acc[dd][13]);
                            acc[dd][14] = fmaf(xx, w3.z, acc[dd][14]);
                            acc[dd][15] = fmaf(xx, w3.w, acc[dd][15]);
                        }
                    }
                }
            }
        }
    }

    if (MODE == 2) {
        if (active) {
            float mx[4] = { -FLT_MAX, -FLT_MAX, -FLT_MAX, -FLT_MAX };
#pragma unroll
            for (int o = 0; o < CO; ++o) {
                const float mu = g_stats[(n * CO + o) * 2 + 0];
                const float is = g_stats[(n * CO + o) * 2 + 1];
                const float bo = b[o], mo = m[o];
#pragma unroll
                for (int dd = 0; dd < 4; ++dd) {
                    float v = (acc[dd][o] + bo) * mo;
                    v = (v - mu) * is;
                    v = fminf(fmaxf(v, -1.f), 1.f) * mo;
                    mx[dd] = fmaxf(mx[dd], v);
                }
            }
#pragma unroll
            for (int dd = 0; dd < 4; ++dd)
                if (d0 + dd < DOUT)
                    yout[(size_t)n * SP + ((d0 + dd) * DOUT + h) * DOUT + tx] = mx[dd];
        }
        return;
    }

    // MODE 0/1: bias+m, optional y store, block-level sum/sumsq partials
    __shared__ float redS[4][CO];
    __shared__ float redQ[4][CO];

#pragma unroll
    for (int o = 0; o < CO; ++o) {
        float s = 0.f, q = 0.f;
        if (active) {
            const float bo = b[o], mo = m[o];
#pragma unroll
            for (int dd = 0; dd < 4; ++dd) {
                if (d0 + dd < DOUT) {
                    const float v = (acc[dd][o] + bo) * mo;
                    s += v; q += v * v;
                    if (MODE == 1)
                        yout[(size_t)(n * CO + o) * SP + ((d0 + dd) * DOUT + h) * DOUT + tx] = v;
                }
            }
        }
#pragma unroll
        for (int off = 32; off > 0; off >>= 1) {
            s += __shfl_down(s, off);
            q += __shfl_down(q, off);
        }
        if (tx == 0) { redS[ty][o] = s; redQ[ty][o] = q; }
    }
    __syncthreads();

    if (ty == 0 && tx < CO) {
        const int o = tx;
        const float s = redS[0][o] + redS[1][o] + redS[2][o] + redS[3][o];
        const float q = redQ[0][o] + redQ[1][o] + redQ[2][o] + redQ[3][o];
        const int blk = blockIdx.x + HBLK * blockIdx.y;      // 0..255
        g_psum[(n * CO + o) * NPART + blk] = s;
        g_psq [(n * CO + o) * NPART + blk] = q;
    }
}

// Reduce 256 partials per (n,c) -> mean, invstd
__global__ __launch_bounds__(256) void finalize_stats_kernel()
{
    const int idx = blockIdx.x;              // n*16 + o
    const int tid = threadIdx.x;
    __shared__ float ls[256], lq[256];
    ls[tid] = g_psum[idx * NPART + tid];
    lq[tid] = g_psq [idx * NPART + tid];
    __syncthreads();
    for (int off = 128; off > 0; off >>= 1) {
        if (tid < off) { ls[tid] += ls[tid + off]; lq[tid] += lq[tid + off]; }
        __syncthreads();
    }
    if (tid == 0) {
        const float inv_n = 1.0f / (float)SP;
        const float mean = ls[0] * inv_n;
        const float var  = fmaxf(lq[0] * inv_n - mean * mean, 0.f);
        g_stats[idx * 2 + 0] = mean;
        g_stats[idx * 2 + 1] = rsqrtf(var + 1e-5f);
    }
}

// Memory-bound pass 2 when y was stored: read y, normalize, clamp, *m, max, store
__global__ __launch_bounds__(256) void pass2_ry_kernel(
    const float* __restrict__ y, const float* __restrict__ m,
    float* __restrict__ out)
{
    const int gid = blockIdx.x * 256 + threadIdx.x;
    if (gid >= NB * SP) return;
    const int n  = gid / SP;
    const int sp = gid % SP;

    float mx = -FLT_MAX;
#pragma unroll
    for (int o = 0; o < CO; ++o) {
        const float mu = g_stats[(n * CO + o) * 2 + 0];
        const float is = g_stats[(n * CO + o) * 2 + 1];
        float v = y[(size_t)(n * CO + o) * SP + sp];
        v = (v - mu) * is;
        v = fminf(fmaxf(v, -1.f), 1.f) * m[o];
        mx = fmaxf(mx, v);
    }
    out[gid] = mx;
}

extern "C" void kernel_launch(void* const* d_in, const int* in_sizes, int n_in,
                              void* d_out, int out_size, void* d_ws, size_t ws_size,
                              hipStream_t stream)
{
    const float* x = (const float*)d_in[0];
    const float* w = (const float*)d_in[1];
    const float* b = (const float*)d_in[2];
    const float* m = (const float*)d_in[3];
    float* out = (float*)d_out;

    const dim3 blk(64, 4);
    const dim3 grd(HBLK, DBLK, NB);
    const size_t yBytes = (size_t)NB * CO * SP * sizeof(float);   // ~244 MB

    reorg_w_kernel<<<dim3(1), dim3(256), 0, stream>>>(w);

    if (ws_size >= yBytes) {
        float* y = (float*)d_ws;
        conv_kernel<1><<<grd, blk, 0, stream>>>(x, b, m, y);
        finalize_stats_kernel<<<dim3(NB * CO), dim3(256), 0, stream>>>();
        pass2_ry_kernel<<<dim3((NB * SP + 255) / 256), dim3(256), 0, stream>>>(y, m, out);
    } else {
        conv_kernel<0><<<grd, blk, 0, stream>>>(x, b, m, nullptr);
        finalize_stats_kernel<<<dim3(NB * CO), dim3(256), 0, stream>>>();
        conv_kernel<2><<<grd, blk, 0, stream>>>(x, b, m, out);
    }
}

// Round 11
// 190.206 us; speedup vs baseline: 2.7802x; 1.0185x over previous
//
#include <hip/hip_runtime.h>
#include <hip/hip_bf16.h>
#include <float.h>

// Geometry
#define DI   64
#define DOUT 62
#define CI   3
#define CO   16
#define NB   16
constexpr int SP    = DOUT * DOUT * DOUT;   // 238328
constexpr int HBLK  = 16;                   // h tiles of 4
constexpr int DBLK  = 16;                   // d tiles of 4
constexpr int NPART = HBLK * DBLK;          // 256 partials per (n,c)

// Module BSS scratch (fully rewritten every call)
__device__ float  g_psum[NB * CO * NPART];
__device__ float  g_psq [NB * CO * NPART];
__device__ float  g_stats[NB * CO * 2];
// Reorganized weights: [i][kh][kd][r] -> 16 channels contiguous, float4-aligned.
__device__ float4 g_wr4[CI * 3 * 3 * 3 * 4];   // 324 float4 = 5184 B

__device__ __forceinline__ unsigned short f2bf(float v) {
    __hip_bfloat16 h = __float2bfloat16(v);
    return __builtin_bit_cast(unsigned short, h);
}

// Reorder w[o][i][kd][kh][r] -> g_wr[((i*3+kh)*3+kd)*3+r][o]
__global__ void reorg_w_kernel(const float* __restrict__ w)
{
    float* dst = (float*)g_wr4;
    for (int idx = threadIdx.x; idx < CO * CI * 27; idx += 256) {
        const int o  = idx / 81;
        const int t  = idx % 81;          // i*27 + kd*9 + kh*3 + r
        const int i  = t / 27;
        const int kd = (t % 27) / 9;
        const int kh = (t % 9) / 3;
        const int r  = t % 3;
        dst[((((i * 3 + kh) * 3 + kd) * 3) + r) * 16 + o] = w[idx];
    }
}

// ---------------------------------------------------------------------------
// Tiled conv: block (64,4) -> [4d][4h][62w] x 16ch tile, o-blocked in halves
// of 8 channels (acc[4][8] ~ 75 live VGPRs; R10's monolithic acc[4][16] made
// the compiler re-materialize down to 60 VGPRs with ~40% non-FMA VALU).
// y stored as bf16 pairs (2 channels per uint): 122 MB, L3-resident.
// ---------------------------------------------------------------------------
template <int MODE>  // 0 = stats only, 1 = stats + bf16-y store, 2 = recompute -> out
__global__ __launch_bounds__(256) void conv_kernel(
    const float* __restrict__ x,
    const float* __restrict__ b, const float* __restrict__ m,
    unsigned int* __restrict__ y32,   // MODE1: packed bf16 y
    float* __restrict__ out)          // MODE2: final out
{
    const int tx = threadIdx.x;              // w lane 0..63
    const int ty = threadIdx.y;              // 0..3
    const int h0 = blockIdx.x * 4;
    const int d0 = blockIdx.y * 4;
    const int n  = blockIdx.z;
    const int h  = h0 + ty;

    __shared__ float xs[3 * 6 * 6 * 64];     // ((i*6+p)*6+hr)*64 + w

    const float* xn = x + (size_t)n * CI * DI * DI * DI;
    for (int rr = ty; rr < 108; rr += 4) {
        const int i  = rr / 36;
        const int rm = rr % 36;
        const int dg = min(d0 + rm / 6, DI - 1);
        const int hg = min(h0 + rm % 6, DI - 1);
        xs[rr * 64 + tx] = xn[((i * DI + dg) * DI + hg) * DI + tx];
    }
    __syncthreads();

    const bool active = (tx < DOUT) && (h < DOUT);

    __shared__ float redS[4][CO];
    __shared__ float redQ[4][CO];

    float mx[4];                              // MODE2: channel-max across halves
#pragma unroll
    for (int dd = 0; dd < 4; ++dd) mx[dd] = -FLT_MAX;

#pragma unroll
    for (int oh = 0; oh < 2; ++oh) {          // channel half: o = oh*8 .. oh*8+7
        float acc[4][8];
#pragma unroll
        for (int dd = 0; dd < 4; ++dd)
#pragma unroll
            for (int o = 0; o < 8; ++o) acc[dd][o] = 0.f;

        if (active) {
#pragma unroll
            for (int i = 0; i < CI; ++i) {
#pragma unroll
                for (int kh = 0; kh < 3; ++kh) {
                    const float* base = xs + (i * 36 + ty + kh) * 64 + tx;
                    float xv[6][3];
#pragma unroll
                    for (int p = 0; p < 6; ++p) {
                        xv[p][0] = base[p * 384 + 0];
                        xv[p][1] = base[p * 384 + 1];
                        xv[p][2] = base[p * 384 + 2];
                    }
#pragma unroll
                    for (int kd = 0; kd < 3; ++kd) {
#pragma unroll
                        for (int r = 0; r < 3; ++r) {
                            const float4* wq =
                                g_wr4 + ((((i * 3 + kh) * 3 + kd) * 3) + r) * 4 + oh * 2;
                            const float4 w0 = wq[0], w1 = wq[1];
#pragma unroll
                            for (int dd = 0; dd < 4; ++dd) {
                                const float xx = xv[kd + dd][r];
                                acc[dd][0] = fmaf(xx, w0.x, acc[dd][0]);
                                acc[dd][1] = fmaf(xx, w0.y, acc[dd][1]);
                                acc[dd][2] = fmaf(xx, w0.z, acc[dd][2]);
                                acc[dd][3] = fmaf(xx, w0.w, acc[dd][3]);
                                acc[dd][4] = fmaf(xx, w1.x, acc[dd][4]);
                                acc[dd][5] = fmaf(xx, w1.y, acc[dd][5]);
                                acc[dd][6] = fmaf(xx, w1.z, acc[dd][6]);
                                acc[dd][7] = fmaf(xx, w1.w, acc[dd][7]);
                            }
                        }
                    }
                }
            }
        }

        if (MODE == 2) {
            // normalize, clamp, *m, fold into channel max
            if (active) {
#pragma unroll
                for (int o = 0; o < 8; ++o) {
                    const int og = oh * 8 + o;
                    const float mu = g_stats[(n * CO + og) * 2 + 0];
                    const float is = g_stats[(n * CO + og) * 2 + 1];
                    const float bo = b[og], mo = m[og];
#pragma unroll
                    for (int dd = 0; dd < 4; ++dd) {
                        float v = (acc[dd][o] + bo) * mo;
                        v = (v - mu) * is;
                        v = fminf(fmaxf(v, -1.f), 1.f) * mo;
                        mx[dd] = fmaxf(mx[dd], v);
                    }
                }
            }
        } else {
            // bias+m, stats partials (fp32, pre-rounding), optional bf16-y store
#pragma unroll
            for (int o = 0; o < 8; ++o) {
                const int og = oh * 8 + o;
                float s = 0.f, q = 0.f;
                if (active) {
                    const float bo = b[og], mo = m[og];
#pragma unroll
                    for (int dd = 0; dd < 4; ++dd) {
                        if (d0 + dd < DOUT) {
                            const float v = (acc[dd][o] + bo) * mo;
                            s += v; q += v * v;
                            acc[dd][o] = v;   // keep transformed value for store
                        }
                    }
                }
#pragma unroll
                for (int off = 32; off > 0; off >>= 1) {
                    s += __shfl_down(s, off);
                    q += __shfl_down(q, off);
                }
                if (tx == 0) { redS[ty][og] = s; redQ[ty][og] = q; }
            }
            if (MODE == 1 && active) {
#pragma unroll
                for (int dd = 0; dd < 4; ++dd) {
                    if (d0 + dd < DOUT) {
                        const int sp = ((d0 + dd) * DOUT + h) * DOUT + tx;
#pragma unroll
                        for (int op = 0; op < 4; ++op) {
                            const unsigned int u =
                                (unsigned int)f2bf(acc[dd][2 * op]) |
                                ((unsigned int)f2bf(acc[dd][2 * op + 1]) << 16);
                            y32[(size_t)(n * 8 + oh * 4 + op) * SP + sp] = u;
                        }
                    }
                }
            }
        }
    }

    if (MODE == 2) {
        if (active) {
#pragma unroll
            for (int dd = 0; dd < 4; ++dd)
                if (d0 + dd < DOUT)
                    out[(size_t)n * SP + ((d0 + dd) * DOUT + h) * DOUT + tx] = mx[dd];
        }
        return;
    }

    __syncthreads();
    if (ty == 0 && tx < CO) {
        const int o = tx;
        const float s = redS[0][o] + redS[1][o] + redS[2][o] + redS[3][o];
        const float q = redQ[0][o] + redQ[1][o] + redQ[2][o] + redQ[3][o];
        const int blk = blockIdx.x + HBLK * blockIdx.y;      // 0..255
        g_psum[(n * CO + o) * NPART + blk] = s;
        g_psq [(n * CO + o) * NPART + blk] = q;
    }
}

// Reduce 256 partials per (n,c) -> mean, invstd
__global__ __launch_bounds__(256) void finalize_stats_kernel()
{
    const int idx = blockIdx.x;              // n*16 + o
    const int tid = threadIdx.x;
    __shared__ float ls[256], lq[256];
    ls[tid] = g_psum[idx * NPART + tid];
    lq[tid] = g_psq [idx * NPART + tid];
    __syncthreads();
    for (int off = 128; off > 0; off >>= 1) {
        if (tid < off) { ls[tid] += ls[tid + off]; lq[tid] += lq[tid + off]; }
        __syncthreads();
    }
    if (tid == 0) {
        const float inv_n = 1.0f / (float)SP;
        const float mean = ls[0] * inv_n;
        const float var  = fmaxf(lq[0] * inv_n - mean * mean, 0.f);
        g_stats[idx * 2 + 0] = mean;
        g_stats[idx * 2 + 1] = rsqrtf(var + 1e-5f);
    }
}

// Pass 2: read packed bf16 y (L3-resident), normalize, clamp, *m, max, store fp32
__global__ __launch_bounds__(256) void pass2_ry_kernel(
    const unsigned int* __restrict__ y32, const float* __restrict__ m,
    float* __restrict__ out)
{
    const int gid = blockIdx.x * 256 + threadIdx.x;
    if (gid >= NB * SP) return;
    const int n  = gid / SP;
    const int sp = gid % SP;

    float mx = -FLT_MAX;
#pragma unroll
    for (int op = 0; op < 8; ++op) {
        const unsigned int u = y32[(size_t)(n * 8 + op) * SP + sp];
        const float v0 = __uint_as_float(u << 16);
        const float v1 = __uint_as_float(u & 0xFFFF0000u);
        const int o0 = 2 * op, o1 = 2 * op + 1;
        float z0 = (v0 - g_stats[(n * CO + o0) * 2 + 0]) * g_stats[(n * CO + o0) * 2 + 1];
        float z1 = (v1 - g_stats[(n * CO + o1) * 2 + 0]) * g_stats[(n * CO + o1) * 2 + 1];
        z0 = fminf(fmaxf(z0, -1.f), 1.f) * m[o0];
        z1 = fminf(fmaxf(z1, -1.f), 1.f) * m[o1];
        mx = fmaxf(mx, fmaxf(z0, z1));
    }
    out[gid] = mx;
}

extern "C" void kernel_launch(void* const* d_in, const int* in_sizes, int n_in,
                              void* d_out, int out_size, void* d_ws, size_t ws_size,
                              hipStream_t stream)
{
    const float* x = (const float*)d_in[0];
    const float* w = (const float*)d_in[1];
    const float* b = (const float*)d_in[2];
    const float* m = (const float*)d_in[3];
    float* out = (float*)d_out;

    const dim3 blk(64, 4);
    const dim3 grd(HBLK, DBLK, NB);
    const size_t yBytes = (size_t)NB * 8 * SP * sizeof(unsigned int);   // ~122 MB

    reorg_w_kernel<<<dim3(1), dim3(256), 0, stream>>>(w);

    if (ws_size >= yBytes) {
        unsigned int* y = (unsigned int*)d_ws;
        conv_kernel<1><<<grd, blk, 0, stream>>>(x, b, m, y, nullptr);
        finalize_stats_kernel<<<dim3(NB * CO), dim3(256), 0, stream>>>();
        pass2_ry_kernel<<<dim3((NB * SP + 255) / 256), dim3(256), 0, stream>>>(y, m, out);
    } else {
        conv_kernel<0><<<grd, blk, 0, stream>>>(x, b, m, nullptr, nullptr);
        finalize_stats_kernel<<<dim3(NB * CO), dim3(256), 0, stream>>>();
        conv_kernel<2><<<grd, blk, 0, stream>>>(x, b, m, nullptr, out);
    }
}

// Round 12
// 108.017 us; speedup vs baseline: 4.8957x; 1.7609x over previous
//
#include <hip/hip_runtime.h>
#include <hip/hip_bf16.h>
#include <float.h>

#define DI   64
#define DOUT 62
#define CI   3
#define CO   16
#define NB   16
constexpr int SP    = DOUT * DOUT * DOUT;    // 238328
constexpr int NPART = 256;                   // 16 h-tiles x 16 d-tiles
constexpr long long XTOT = (long long)NB * CI * DI * DI * DI;

typedef __attribute__((ext_vector_type(8))) short bf16x8;
typedef __attribute__((ext_vector_type(4))) float f32x4;

// Module BSS scratch (fully rewritten every call)
__device__ float g_psum[NB * CO * NPART];
__device__ float g_psq [NB * CO * NPART];
__device__ float g_stats[NB * CO * 2];
// Prepacked per-lane B fragments: [t=K-step][lane][4 dwords] (bf16 pairs)
__device__ uint4 g_wb4[4 * 64];

__device__ __forceinline__ unsigned short f2bf(float v) {
    __hip_bfloat16 h = __float2bfloat16(v);
    return __builtin_bit_cast(unsigned short, h);
}

// Pack B[k][o]: k = t*32 + (lane>>4)*8 + j ; tap k -> (g=k>>2, r=k&3),
// g -> (i,kd,kh). Zero for r==3 or g>=27 (K padding).
__global__ void reorg_w_kernel(const float* __restrict__ w)
{
    unsigned int* dst = (unsigned int*)g_wb4;
    for (int d = threadIdx.x; d < 4 * 64 * 4; d += 256) {
        const int t    = d >> 8;
        const int lane = (d >> 2) & 63;
        const int dw   = d & 3;
        const int o    = lane & 15, q = lane >> 4;
        unsigned int u = 0;
        for (int half = 0; half < 2; ++half) {
            const int j = dw * 2 + half;
            const int k = t * 32 + q * 8 + j;
            const int g = k >> 2, r = k & 3;
            float val = 0.f;
            if (g < 27 && r < 3) {
                const int i = g / 9, kd = (g % 9) / 3, kh = g % 3;
                val = w[o * 81 + i * 27 + kd * 9 + kh * 3 + r];
            }
            u |= ((unsigned int)f2bf(val)) << (16 * half);
        }
        dst[d] = u;
    }
}

// ---------------------------------------------------------------------------
// MFMA implicit-GEMM conv. Block (64,4): wave ty owns depth row d0+ty.
// Per wave: 4 hh x 4 w-tiles, each tile = D[16 pos x 16 ch] via 4 MFMA (K=128).
// A-taps read from two-phase bf16 LDS slab (even/odd w-interleave, +1 pad).
// MODE 0: stats only. 1: stats + y[n][sp][16ch] bf16. 2: recompute -> out.
// ---------------------------------------------------------------------------
template <int MODE>
__global__ __launch_bounds__(256) void conv_mfma_kernel(
    const float* __restrict__ x,
    const float* __restrict__ b, const float* __restrict__ m,
    unsigned short* __restrict__ y16, float* __restrict__ out)
{
    constexpr int RSTR = 33;                 // dword row stride (+1 bank pad)
    constexpr int PH   = 3 * 36 * RSTR;      // 3564 dwords per phase
    __shared__ unsigned int xs[2 * PH];      // 28512 B
    __shared__ float redS[4][CO], redQ[4][CO];

    const int lane = threadIdx.x, ty = threadIdx.y;
    const int h0 = blockIdx.x * 4, d0 = blockIdx.y * 4, n = blockIdx.z;

    // ---- stage: x fp32 -> bf16, two phase copies (rowidx == rr) ----
    for (int rr = ty; rr < 108; rr += 4) {
        const int i = rr / 36, rm = rr % 36, p = rm / 6, hr = rm % 6;
        const int dg = min(d0 + p, DI - 1), hg = min(h0 + hr, DI - 1);
        const long long rowbase = (((long long)n * CI + i) * DI + dg) * DI * DI
                                  + (long long)hg * DI;
        const int t = lane & 31, odd = lane >> 5;
        unsigned int u;
        if (!odd) {
            const float2 v = *(const float2*)(x + rowbase + 2 * t);  // 8B aligned
            u = (unsigned)f2bf(v.x) | ((unsigned)f2bf(v.y) << 16);
        } else {
            long long f = rowbase + 2 * t + 1;
            f = (f > XTOT - 2) ? (XTOT - 2) : f;                      // OOB guard
            const float a0 = x[f], a1 = x[f + 1];
            u = (unsigned)f2bf(a0) | ((unsigned)f2bf(a1) << 16);
        }
        xs[odd * PH + rr * RSTR + t] = u;
    }
    __syncthreads();

    const int c = lane & 15, q = lane >> 4;
    const int phase = c & 1, chalf = c >> 1;

    // Resident B fragments
    bf16x8 wf[4];
#pragma unroll
    for (int t = 0; t < 4; ++t)
        wf[t] = __builtin_bit_cast(bf16x8, g_wb4[t * 64 + lane]);

    // Per-lane tap-row offsets (dwords), tile part added later
    int RB[4][2];
#pragma unroll
    for (int t = 0; t < 4; ++t)
#pragma unroll
        for (int s = 0; s < 2; ++s) {
            int g = t * 8 + q * 2 + s;
            if (g > 26) g = 26;                     // pad groups read junk*0
            const int i = g / 9, kd = (g % 9) / 3, kh = g % 3;
            RB[t][s] = (i * 36 + kd * 6 + kh) * RSTR;
        }

    const float bc = b[c], mc = m[c];
    float mu = 0.f, is = 1.f;
    if (MODE == 2) {
        mu = g_stats[(n * CO + c) * 2 + 0];
        is = g_stats[(n * CO + c) * 2 + 1];
    }

    const int d = d0 + ty;
    const bool dvalid = d < DOUT;
    float sSum = 0.f, qSum = 0.f;

    if (dvalid) {
#pragma unroll
        for (int hh = 0; hh < 4; ++hh) {
            const int h = h0 + hh;
            if (h < DOUT) {
                const int tb = (ty * 6 + hh) * RSTR + (phase ? PH : 0) + chalf;
#pragma unroll
                for (int wt = 0; wt < 4; ++wt) {
                    const int tb2 = tb + wt * 8;
                    f32x4 acc = {0.f, 0.f, 0.f, 0.f};
#pragma unroll
                    for (int t = 0; t < 4; ++t) {
                        const int i0 = tb2 + RB[t][0];
                        const int i1 = tb2 + RB[t][1];
                        uint4 av;
                        av.x = xs[i0]; av.y = xs[i0 + 1];
                        av.z = xs[i1]; av.w = xs[i1 + 1];
                        const bf16x8 af = __builtin_bit_cast(bf16x8, av);
                        acc = __builtin_amdgcn_mfma_f32_16x16x32_bf16(af, wf[t], acc, 0, 0, 0);
                    }
                    // epilogue: lane holds channel c at positions wbase+reg
                    const int wbase = wt * 16 + q * 4;
                    const size_t spbase = ((size_t)(d * DOUT + h)) * DOUT + wbase;
                    if (MODE == 2) {
#pragma unroll
                        for (int r = 0; r < 4; ++r) {
                            float v = (acc[r] + bc) * mc;
                            float z = (v - mu) * is;
                            z = fminf(fmaxf(z, -1.f), 1.f) * mc;
#pragma unroll
                            for (int off = 1; off < 16; off <<= 1)
                                z = fmaxf(z, __shfl_xor(z, off));
                            if (c == 0 && wbase + r < DOUT)
                                out[(size_t)n * SP + spbase + r] = z;
                        }
                    } else {
                        unsigned short* yb =
                            (MODE == 1) ? y16 + (((size_t)n * SP + spbase) * CO + c) : nullptr;
#pragma unroll
                        for (int r = 0; r < 4; ++r) {
                            if (wbase + r < DOUT) {
                                const float v = (acc[r] + bc) * mc;
                                sSum += v; qSum += v * v;
                                if (MODE == 1) yb[(size_t)r * CO] = f2bf(v);
                            }
                        }
                    }
                }
            }
        }
    }

    if (MODE != 2) {
        // channel-c totals: reduce across the 4 quarter-waves, then 4 waves
        sSum += __shfl_xor(sSum, 16); qSum += __shfl_xor(qSum, 16);
        sSum += __shfl_xor(sSum, 32); qSum += __shfl_xor(qSum, 32);
        if (lane < 16) { redS[ty][c] = sSum; redQ[ty][c] = qSum; }
        __syncthreads();
        if (ty == 0 && lane < 16) {
            const float s  = redS[0][lane] + redS[1][lane] + redS[2][lane] + redS[3][lane];
            const float qq = redQ[0][lane] + redQ[1][lane] + redQ[2][lane] + redQ[3][lane];
            const int blk = blockIdx.y * 16 + blockIdx.x;       // 0..255
            g_psum[(n * CO + lane) * NPART + blk] = s;
            g_psq [(n * CO + lane) * NPART + blk] = qq;
        }
    }
}

// Reduce 256 partials per (n,c) -> mean, invstd
__global__ __launch_bounds__(256) void finalize_stats_kernel()
{
    const int idx = blockIdx.x;              // n*16 + o
    const int tid = threadIdx.x;
    __shared__ float ls[256], lq[256];
    ls[tid] = g_psum[idx * NPART + tid];
    lq[tid] = g_psq [idx * NPART + tid];
    __syncthreads();
    for (int off = 128; off > 0; off >>= 1) {
        if (tid < off) { ls[tid] += ls[tid + off]; lq[tid] += lq[tid + off]; }
        __syncthreads();
    }
    if (tid == 0) {
        const float inv_n = 1.0f / (float)SP;
        const float mean = ls[0] * inv_n;
        const float var  = fmaxf(lq[0] * inv_n - mean * mean, 0.f);
        g_stats[idx * 2 + 0] = mean;
        g_stats[idx * 2 + 1] = rsqrtf(var + 1e-5f);
    }
}

// Pass 2: read y[n][sp][16ch] bf16 (32B/thread, coalesced), norm/clamp/*m/max
__global__ __launch_bounds__(256) void pass2_kernel(
    const unsigned short* __restrict__ y16, const float* __restrict__ m,
    float* __restrict__ out)
{
    const int n  = blockIdx.y;
    const int sp = blockIdx.x * 256 + threadIdx.x;
    if (sp >= SP) return;
    const uint4* p = (const uint4*)(y16 + ((size_t)n * SP + sp) * CO);
    const uint4 u0 = p[0], u1 = p[1];
    const float* st = g_stats + n * CO * 2;
    float mx = -FLT_MAX;
    unsigned int uu[8] = {u0.x, u0.y, u0.z, u0.w, u1.x, u1.y, u1.z, u1.w};
#pragma unroll
    for (int k = 0; k < 8; ++k) {
        const int o = 2 * k;
        const float v0 = __uint_as_float(uu[k] << 16);
        const float v1 = __uint_as_float(uu[k] & 0xFFFF0000u);
        float z0 = (v0 - st[o * 2]) * st[o * 2 + 1];
        float z1 = (v1 - st[(o + 1) * 2]) * st[(o + 1) * 2 + 1];
        z0 = fminf(fmaxf(z0, -1.f), 1.f) * m[o];
        z1 = fminf(fmaxf(z1, -1.f), 1.f) * m[o + 1];
        mx = fmaxf(mx, fmaxf(z0, z1));
    }
    out[(size_t)n * SP + sp] = mx;
}

extern "C" void kernel_launch(void* const* d_in, const int* in_sizes, int n_in,
                              void* d_out, int out_size, void* d_ws, size_t ws_size,
                              hipStream_t stream)
{
    const float* x = (const float*)d_in[0];
    const float* w = (const float*)d_in[1];
    const float* b = (const float*)d_in[2];
    const float* m = (const float*)d_in[3];
    float* out = (float*)d_out;

    const dim3 blk(64, 4);
    const dim3 grd(16, 16, NB);
    const size_t yBytes = (size_t)NB * SP * CO * 2;   // ~122 MB

    reorg_w_kernel<<<dim3(1), dim3(256), 0, stream>>>(w);

    if (ws_size >= yBytes) {
        unsigned short* y = (unsigned short*)d_ws;
        conv_mfma_kernel<1><<<grd, blk, 0, stream>>>(x, b, m, y, nullptr);
        finalize_stats_kernel<<<dim3(NB * CO), dim3(256), 0, stream>>>();
        pass2_kernel<<<dim3((SP + 255) / 256, NB), dim3(256), 0, stream>>>(y, m, out);
    } else {
        conv_mfma_kernel<0><<<grd, blk, 0, stream>>>(x, b, m, nullptr, nullptr);
        finalize_stats_kernel<<<dim3(NB * CO), dim3(256), 0, stream>>>();
        conv_mfma_kernel<2><<<grd, blk, 0, stream>>>(x, b, m, nullptr, out);
    }
}